// Round 1
// baseline (180.384 us; speedup 1.0000x reference)
//
#include <hip/hip_runtime.h>
#include <hip/hip_bf16.h>
#include <cmath>

// Problem constants (from reference): B=64, T=128, F=188, H=16
#define NROWS   8192      // B*T
#define FDIM    188
#define HDIM    16
#define NCONT   177       // F - 11
#define XSTRIDE 3008      // F*H
#define CFPAD   178       // padded cf-dim for transposed cont-weight LDS tile

// LDS offsets inside sCat (flat float array): categorical weights then biases
//  W2a:   0..127   (4*16*2)
//  W3 : 128..223   (2*16*3)
//  W4 : 224..287   (1*16*4)
//  W6 : 288..383   (1*16*6)
//  W7 : 384..719   (3*16*7)
//  b2a: 720..727, b3: 728..733, b4: 734..737, b6: 738..743, b7: 744..764
#define CAT_TOTAL 765

__global__ __launch_bounds__(256)
void tab_dec_kernel(const float* __restrict__ x,
                    const float* __restrict__ W2a, const float* __restrict__ b2a,
                    const float* __restrict__ W3,  const float* __restrict__ b3,
                    const float* __restrict__ W4,  const float* __restrict__ b4,
                    const float* __restrict__ W6,  const float* __restrict__ b6,
                    const float* __restrict__ W7,  const float* __restrict__ b7,
                    const float* __restrict__ Wc,  const float* __restrict__ bc,
                    const float* __restrict__ eps,
                    float* __restrict__ out)
{
    // Transposed continuous weights: sWcT[c][cf], c = d*2+o in [0,32), cf in [0,177)
    // Consecutive lanes have consecutive cf -> consecutive LDS addresses -> 2 lanes/bank (free).
    __shared__ float sWcT[32 * CFPAD];
    __shared__ float sbcT[2 * CFPAD];
    __shared__ float sCat[CAT_TOTAL];

    const int tid = threadIdx.x;

    // ---- Stage weights into LDS (once per block) ----
    for (int i = tid; i < NCONT * 32; i += 256) {
        int cf = i >> 5;          // i / 32
        int c  = i & 31;          // d*2+o
        sWcT[c * CFPAD + cf] = Wc[i];
    }
    for (int i = tid; i < NCONT * 2; i += 256) {
        int cf = i >> 1;
        int o  = i & 1;
        sbcT[o * CFPAD + cf] = bc[i];
    }
    for (int i = tid; i < 128; i += 256) sCat[i]       = W2a[i];
    for (int i = tid; i <  96; i += 256) sCat[128 + i] = W3[i];
    for (int i = tid; i <  64; i += 256) sCat[224 + i] = W4[i];
    for (int i = tid; i <  96; i += 256) sCat[288 + i] = W6[i];
    for (int i = tid; i < 336; i += 256) sCat[384 + i] = W7[i];
    if (tid <  8) sCat[720 + tid] = b2a[tid];
    if (tid <  6) sCat[728 + tid] = b3[tid];
    if (tid <  4) sCat[734 + tid] = b4[tid];
    if (tid <  6) sCat[738 + tid] = b6[tid];
    if (tid < 21) sCat[744 + tid] = b7[tid];
    __syncthreads();

    const int total  = NROWS * FDIM;
    const int stride = gridDim.x * blockDim.x;

    for (int idx = blockIdx.x * blockDim.x + tid; idx < total; idx += stride) {
        const int n = idx / FDIM;
        const int f = idx - n * FDIM;

        // 16 contiguous floats for this (row, feature): 4 aligned float4 loads.
        const float4* xp = reinterpret_cast<const float4*>(
            x + (size_t)n * XSTRIDE + (size_t)f * HDIM);
        float4 v0 = xp[0], v1 = xp[1], v2 = xp[2], v3 = xp[3];
        float xv[16] = { v0.x, v0.y, v0.z, v0.w,
                         v1.x, v1.y, v1.z, v1.w,
                         v2.x, v2.y, v2.z, v2.w,
                         v3.x, v3.y, v3.z, v3.w };

        float res;
        if (f >= 11) {
            // Continuous head: dec = x . Wc[cf] + bc[cf]; tanh / sigmoid / sample
            const int cf = f - 11;
            float m  = sbcT[cf];            // bias for o=0 (mean)
            float sg = sbcT[CFPAD + cf];    // bias for o=1 (std logit)
            #pragma unroll
            for (int d = 0; d < 16; ++d) {
                m  = fmaf(xv[d], sWcT[(2 * d)     * CFPAD + cf], m);
                sg = fmaf(xv[d], sWcT[(2 * d + 1) * CFPAD + cf], sg);
            }
            const float mean = tanhf(m);
            const float stdv = 1.0f / (1.0f + __expf(-sg));
            res = fmaf(stdv, eps[(size_t)n * NCONT + cf], mean);
        } else {
            // Categorical head: argmax over odim logits (first-max tie-break like jnp.argmax)
            int g, wo, bo, odim;
            if (f < 4)      { g = f;     wo = 0;   bo = 720; odim = 2; }
            else if (f < 6) { g = f - 4; wo = 128; bo = 728; odim = 3; }
            else if (f < 7) { g = 0;     wo = 224; bo = 734; odim = 4; }
            else if (f < 8) { g = 0;     wo = 288; bo = 738; odim = 6; }
            else            { g = f - 8; wo = 384; bo = 744; odim = 7; }
            const float* W = sCat + wo + g * HDIM * odim;   // layout [d][o]
            const float* bb = sCat + bo + g * odim;
            float best = -1e30f;
            int   bi   = 0;
            for (int o = 0; o < odim; ++o) {
                float acc = bb[o];
                #pragma unroll
                for (int d = 0; d < 16; ++d) acc = fmaf(xv[d], W[d * odim + o], acc);
                if (acc > best) { best = acc; bi = o; }   // strict > keeps first max
            }
            res = (float)bi;
        }
        out[idx] = res;
    }
}

extern "C" void kernel_launch(void* const* d_in, const int* in_sizes, int n_in,
                              void* d_out, int out_size, void* d_ws, size_t ws_size,
                              hipStream_t stream) {
    const float* x   = (const float*)d_in[0];
    const float* W2a = (const float*)d_in[1];
    const float* b2a = (const float*)d_in[2];
    const float* W3  = (const float*)d_in[3];
    const float* b3  = (const float*)d_in[4];
    const float* W4  = (const float*)d_in[5];
    const float* b4  = (const float*)d_in[6];
    const float* W6  = (const float*)d_in[7];
    const float* b6  = (const float*)d_in[8];
    const float* W7  = (const float*)d_in[9];
    const float* b7  = (const float*)d_in[10];
    const float* Wc  = (const float*)d_in[11];
    const float* bc  = (const float*)d_in[12];
    const float* eps = (const float*)d_in[13];
    float* out = (float*)d_out;

    // 1280 blocks = 5 per CU; grid-stride loop covers 8192*188 elements
    // (~4.7 elements/thread). LDS 26.6 KB/block -> LDS allows 5 blocks/CU.
    dim3 grid(1280), block(256);
    hipLaunchKernelGGL(tab_dec_kernel, grid, block, 0, stream,
                       x, W2a, b2a, W3, b3, W4, b4, W6, b6, W7, b7, Wc, bc, eps, out);
}